// Round 3
// baseline (625.536 us; speedup 1.0000x reference)
//
#include <hip/hip_runtime.h>
#include <math.h>

#define B_DIM 4
#define C_DIM 256
#define N_DIM 2048
#define H_DIM 8
#define HD    64
#define HB    (H_DIM * B_DIM)   // 32

typedef __attribute__((ext_vector_type(8))) short bf16x8;
typedef __attribute__((ext_vector_type(4))) float f32x4;

static __device__ __forceinline__ short f2bf(float f) {
    unsigned u = __builtin_bit_cast(unsigned, f);
    u += 0x7fffu + ((u >> 16) & 1u);
    return (short)(u >> 16);
}

// ---------------------------------------------------------------------------
// Projection: Z = W (O x C) @ X[b] (C x N) (+ bias), fp32 compute.
// mode 0: bf16 out (h,b,n,d); mode 2: fp32 out (b,n,d) [O=64];
// mode 3: fp32 out transposed (h,b,d,n).
// ---------------------------------------------------------------------------
__global__ __launch_bounds__(256) void proj_kernel(
    const float* __restrict__ X,     // (B, C, N)
    const float* __restrict__ W,     // (O, C)
    const float* __restrict__ bias,  // (O) or nullptr
    void* __restrict__ outp, int mode)
{
    const int b  = blockIdx.z;
    const int o0 = blockIdx.y * 64;
    const int n0 = blockIdx.x * 64;

    __shared__ float Wl[16][65];
    __shared__ float Xl[16][65];

    const int t  = threadIdx.x;
    const int tn = t & 15;
    const int to = t >> 4;

    float acc[4][4];
#pragma unroll
    for (int a = 0; a < 4; ++a)
#pragma unroll
        for (int c = 0; c < 4; ++c) acc[a][c] = 0.f;

    for (int c0 = 0; c0 < C_DIM; c0 += 16) {
#pragma unroll
        for (int i = 0; i < 4; ++i) {
            int idx = t + i * 256;
            int oo = idx >> 4, cc = idx & 15;
            Wl[cc][oo] = W[(size_t)(o0 + oo) * C_DIM + c0 + cc];
            int cc2 = idx >> 6, nn = idx & 63;
            Xl[cc2][nn] = X[((size_t)b * C_DIM + c0 + cc2) * N_DIM + n0 + nn];
        }
        __syncthreads();
#pragma unroll
        for (int cc = 0; cc < 16; ++cc) {
            float wr[4], xr[4];
#pragma unroll
            for (int j = 0; j < 4; ++j) { wr[j] = Wl[cc][to * 4 + j]; xr[j] = Xl[cc][tn * 4 + j]; }
#pragma unroll
            for (int jo = 0; jo < 4; ++jo)
#pragma unroll
                for (int jn = 0; jn < 4; ++jn)
                    acc[jo][jn] = fmaf(wr[jo], xr[jn], acc[jo][jn]);
        }
        __syncthreads();
    }

#pragma unroll
    for (int jo = 0; jo < 4; ++jo) {
        int o = o0 + to * 4 + jo;
        float bv = bias ? bias[o] : 0.f;
        int h = o >> 6, d = o & 63;
#pragma unroll
        for (int jn = 0; jn < 4; ++jn) {
            int n = n0 + tn * 4 + jn;
            float v = acc[jo][jn] + bv;
            if (mode == 0) {
                ((short*)outp)[(((size_t)h * B_DIM + b) * N_DIM + n) * HD + d] = f2bf(v);
            } else if (mode == 2) {
                ((float*)outp)[((size_t)b * N_DIM + n) * HD + d] = v;
            } else {  // mode 3
                ((float*)outp)[(((size_t)h * B_DIM + b) * HD + d) * N_DIM + n] = v;
            }
        }
    }
}

// ---------------------------------------------------------------------------
// Row sums: RSp[ms][hb][n] = sum over half m-range of exp(Q[n].K[m]).
// No max subtraction (|E| <~ 52, exp fits fp32/bf16). No LDS, no barriers.
// ---------------------------------------------------------------------------
__global__ __launch_bounds__(256, 8) void rowsum_mfma(
    const short* __restrict__ Q, const short* __restrict__ K,
    float* __restrict__ RSp)
{
    const int hb = blockIdx.y;
    const int n0 = blockIdx.x * 64;
    const int mbeg = blockIdx.z * (N_DIM / 2);
    const int t = threadIdx.x;
    const int wave = t >> 6, lane = t & 63;
    const int lo = lane & 15, quad = lane >> 4;

    const short* qp = Q + ((size_t)hb * N_DIM + n0 + wave * 16 + lo) * HD + quad * 8;
    const bf16x8 a0 = *(const bf16x8*)qp;
    const bf16x8 a1 = *(const bf16x8*)(qp + 32);

    float sm[4] = {0.f, 0.f, 0.f, 0.f};
    const short* kbase = K + (size_t)hb * N_DIM * HD + quad * 8;

    for (int m0 = mbeg; m0 < mbeg + N_DIM / 2; m0 += 64) {
#pragma unroll
        for (int mt = 0; mt < 4; ++mt) {
            const short* kp = kbase + (size_t)(m0 + mt * 16 + lo) * HD;
            bf16x8 b0 = *(const bf16x8*)kp;
            bf16x8 b1 = *(const bf16x8*)(kp + 32);
            f32x4 c = {0.f, 0.f, 0.f, 0.f};
            c = __builtin_amdgcn_mfma_f32_16x16x32_bf16(a0, b0, c, 0, 0, 0);
            c = __builtin_amdgcn_mfma_f32_16x16x32_bf16(a1, b1, c, 0, 0, 0);
#pragma unroll
            for (int r = 0; r < 4; ++r) sm[r] += __expf(c[r]);
        }
    }

#pragma unroll
    for (int s = 1; s < 16; s <<= 1)
#pragma unroll
        for (int r = 0; r < 4; ++r) sm[r] += __shfl_xor(sm[r], s);

    if (lo == 0) {
        int row = n0 + wave * 16 + quad * 4;
#pragma unroll
        for (int r = 0; r < 4; ++r)
            RSp[((size_t)blockIdx.z * HB + hb) * N_DIM + row + r] = sm[r];
    }
}

// SC[hb][n] = 1 / (RSp[0][hb][n] + RSp[1][hb][n])
__global__ __launch_bounds__(256) void inv_kernel(
    const float* __restrict__ RSp, float* __restrict__ SC)
{
    int i = (blockIdx.x * 256 + threadIdx.x) * 4;
#pragma unroll
    for (int j = 0; j < 4; ++j)
        SC[i + j] = 1.f / (RSp[i + j] + RSp[(size_t)HB * N_DIM + i + j]);
}

// V2t[hb][d][n] = bf16( Vf[hb][d][n] * SC[hb][n] )
__global__ __launch_bounds__(256) void scale_v(
    const float* __restrict__ Vf, const float* __restrict__ SC,
    short* __restrict__ V2)
{
    int id = blockIdx.x * 256 + threadIdx.x;   // 0 .. 524287
    int ng = id & 255;
    int hd = id >> 8;                           // hb*64 + d
    int hb = hd >> 6;
    size_t base = (size_t)hd * N_DIM + ng * 8;
    const float* vp = Vf + base;
    const float* sp = SC + (size_t)hb * N_DIM + ng * 8;
    bf16x8 o;
#pragma unroll
    for (int i = 0; i < 8; ++i) o[i] = f2bf(vp[i] * sp[i]);
    *(bf16x8*)(V2 + base) = o;
}

// out[h,b,n,d] = YP[b,n,d] / (1 + gamma[h])  (attn partials atomically added later)
__global__ __launch_bounds__(256) void init_out(
    const float* __restrict__ YP, const float* __restrict__ gamma,
    float* __restrict__ out)
{
    size_t flat = ((size_t)blockIdx.x * 256 + threadIdx.x) * 4;
    int d  = flat & 63;
    int n  = (flat >> 6) & (N_DIM - 1);
    int hb = (int)(flat >> 17);
    int h = hb >> 2, b = hb & 3;
    float inv = 1.f / (1.f + gamma[h]);
    float4 yp = *(const float4*)(YP + ((size_t)b * N_DIM + n) * HD + d);
    yp.x *= inv; yp.y *= inv; yp.z *= inv; yp.w *= inv;
    *(float4*)(out + flat) = yp;
}

// ---------------------------------------------------------------------------
// attnout: out[m,d] += g/(1+g) * sum_n exp(Q[n].K[m]) * V''[n,d]
// Block = (m-tile 64, hb, n-half). No barriers; P through per-wave LDS rows.
// ---------------------------------------------------------------------------
__global__ __launch_bounds__(256, 8) void attnout_mfma(
    const short* __restrict__ Q, const short* __restrict__ K,
    const short* __restrict__ V2t,   // (hb, d, n) bf16, pre-scaled by 1/rowsum
    const float* __restrict__ gamma,
    float* __restrict__ out)         // (H, B, N, HD) fp32, pre-initialized
{
    const int hb = blockIdx.y;
    const int h = hb >> 2;
    const int m0 = blockIdx.x * 64;
    const int nbeg = blockIdx.z * (N_DIM / 2);

    __shared__ short Pl[64][72];   // [m][n] bf16

    const int t = threadIdx.x;
    const int wave = t >> 6, lane = t & 63;
    const int lo = lane & 15, quad = lane >> 4;

    const short* kp = K + ((size_t)hb * N_DIM + m0 + wave * 16 + lo) * HD + quad * 8;
    const bf16x8 bk0 = *(const bf16x8*)kp;
    const bf16x8 bk1 = *(const bf16x8*)(kp + 32);

    f32x4 oacc[4];
#pragma unroll
    for (int dt = 0; dt < 4; ++dt) oacc[dt] = (f32x4){0.f, 0.f, 0.f, 0.f};

    const short* qbase = Q + (size_t)hb * N_DIM * HD + quad * 8;
    const short* vbase = V2t + (size_t)hb * HD * N_DIM + quad * 8;
    short* prow = &Pl[wave * 16 + lo][0];

    for (int n0 = nbeg; n0 < nbeg + N_DIM / 2; n0 += 64) {
        // QK -> P (unnormalized exp), per-wave LDS rows
#pragma unroll
        for (int nt = 0; nt < 4; ++nt) {
            const short* qp2 = qbase + (size_t)(n0 + nt * 16 + lo) * HD;
            bf16x8 a0 = *(const bf16x8*)qp2;
            bf16x8 a1 = *(const bf16x8*)(qp2 + 32);
            f32x4 c = {0.f, 0.f, 0.f, 0.f};
            c = __builtin_amdgcn_mfma_f32_16x16x32_bf16(a0, bk0, c, 0, 0, 0);
            c = __builtin_amdgcn_mfma_f32_16x16x32_bf16(a1, bk1, c, 0, 0, 0);
            short4 pk;
            pk.x = f2bf(__expf(c[0]));
            pk.y = f2bf(__expf(c[1]));
            pk.z = f2bf(__expf(c[2]));
            pk.w = f2bf(__expf(c[3]));
            *(short4*)(prow + nt * 16 + quad * 4) = pk;
        }
        // PV
#pragma unroll
        for (int ks = 0; ks < 2; ++ks) {
            bf16x8 ap = *(const bf16x8*)(prow + ks * 32 + quad * 8);
#pragma unroll
            for (int dt = 0; dt < 4; ++dt) {
                const short* vp = vbase + (size_t)(dt * 16 + lo) * N_DIM + n0 + ks * 32;
                bf16x8 bv = *(const bf16x8*)vp;
                oacc[dt] = __builtin_amdgcn_mfma_f32_16x16x32_bf16(ap, bv, oacc[dt], 0, 0, 0);
            }
        }
    }

    const float g = gamma[h];
    const float ginv = g / (1.f + g);
#pragma unroll
    for (int dt = 0; dt < 4; ++dt) {
        int d = dt * 16 + lo;
#pragma unroll
        for (int r = 0; r < 4; ++r) {
            int m = m0 + wave * 16 + quad * 4 + r;
            atomicAdd(&out[((size_t)hb * N_DIM + m) * HD + d], ginv * oacc[dt][r]);
        }
    }
}

// ---------------------------------------------------------------------------
extern "C" void kernel_launch(void* const* d_in, const int* in_sizes, int n_in,
                              void* d_out, int out_size, void* d_ws, size_t ws_size,
                              hipStream_t stream) {
    const float* x     = (const float*)d_in[0];
    const float* y     = (const float*)d_in[1];
    const float* Wq    = (const float*)d_in[2];
    const float* bq    = (const float*)d_in[3];
    const float* Wk    = (const float*)d_in[4];
    const float* bk    = (const float*)d_in[5];
    const float* Wv    = (const float*)d_in[6];
    const float* bv    = (const float*)d_in[7];
    const float* Wp    = (const float*)d_in[8];
    const float* gamma = (const float*)d_in[9];
    float* out = (float*)d_out;

    const size_t QKV = (size_t)HB * N_DIM * HD;     // 4,194,304 elems
    short* Qb16 = (short*)d_ws;
    short* Kb16 = Qb16 + QKV;
    float* Vft  = (float*)(Kb16 + QKV);              // fp32 (hb,d,n)
    short* V2t  = (short*)(Vft + QKV);               // bf16 (hb,d,n) scaled
    float* YP   = (float*)(V2t + QKV);
    float* RSp  = YP + (size_t)B_DIM * N_DIM * HD;   // 2 * HB * N
    float* SC   = RSp + 2 * (size_t)HB * N_DIM;      // HB * N

    dim3 blk(256);
    proj_kernel<<<dim3(N_DIM / 64, 8, B_DIM), blk, 0, stream>>>(x, Wq, bq, Qb16, 0);
    proj_kernel<<<dim3(N_DIM / 64, 8, B_DIM), blk, 0, stream>>>(y, Wk, bk, Kb16, 0);
    proj_kernel<<<dim3(N_DIM / 64, 8, B_DIM), blk, 0, stream>>>(y, Wv, bv, Vft, 3);
    proj_kernel<<<dim3(N_DIM / 64, 1, B_DIM), blk, 0, stream>>>(y, Wp, nullptr, YP, 2);

    rowsum_mfma<<<dim3(N_DIM / 64, HB, 2), blk, 0, stream>>>(Qb16, Kb16, RSp);
    inv_kernel<<<dim3(HB * N_DIM / 1024), blk, 0, stream>>>(RSp, SC);
    scale_v<<<dim3(2048), blk, 0, stream>>>(Vft, SC, V2t);
    init_out<<<dim3(4096), blk, 0, stream>>>(YP, gamma, out);

    attnout_mfma<<<dim3(N_DIM / 64, HB, 2), blk, 0, stream>>>(Qb16, Kb16, V2t, gamma, out);
}

// Round 5
// 351.961 us; speedup vs baseline: 1.7773x; 1.7773x over previous
//
#include <hip/hip_runtime.h>
#include <math.h>

#define B_DIM 4
#define C_DIM 256
#define N_DIM 2048
#define H_DIM 8
#define HD    64
#define HB    32                 // H*B
#define NTOK  (B_DIM * N_DIM)    // 8192

typedef __attribute__((ext_vector_type(8))) short bf16x8;
typedef __attribute__((ext_vector_type(4))) float f32x4;

static __device__ __forceinline__ short f2bf(float f) {
    unsigned u = __builtin_bit_cast(unsigned, f);
    u += 0x7fffu + ((u >> 16) & 1u);
    return (short)(u >> 16);
}
static __device__ __forceinline__ float bf2f(short s) {
    unsigned u = ((unsigned)(unsigned short)s) << 16;
    return __builtin_bit_cast(float, u);
}

#define MFMA16(A, Bv, Cv) __builtin_amdgcn_mfma_f32_16x16x32_bf16(A, Bv, Cv, 0, 0, 0)

// ---------------------------------------------------------------------------
// cast+transpose: X (B,C,N) fp32 -> Xt (B,N,C) bf16
// ---------------------------------------------------------------------------
__global__ __launch_bounds__(256) void cast_transpose(
    const float* __restrict__ X, short* __restrict__ Xt)
{
    const int b = blockIdx.z, c0 = blockIdx.y * 64, n0 = blockIdx.x * 64;
    __shared__ float L[64][65];
    const int t = threadIdx.x;
    for (int i = t; i < 4096; i += 256) {
        int cc = i >> 6, nn = i & 63;
        L[cc][nn] = X[((size_t)b * C_DIM + c0 + cc) * N_DIM + n0 + nn];
    }
    __syncthreads();
#pragma unroll
    for (int half = 0; half < 2; ++half) {
        int row = half * 32 + (t >> 3);     // n within tile
        int c8 = (t & 7) * 8;               // c within tile
        bf16x8 o;
#pragma unroll
        for (int j = 0; j < 8; ++j) o[j] = f2bf(L[c8 + j][row]);
        *(bf16x8*)(Xt + ((size_t)b * N_DIM + n0 + row) * C_DIM + c0 + c8) = o;
    }
}

// ---------------------------------------------------------------------------
// weights fp32 -> bf16: Wx = Wq (512x256); Wy = [Wk; Wv; Wp] (1088x256)
// ---------------------------------------------------------------------------
__global__ __launch_bounds__(256) void cast_weights(
    const float* __restrict__ Wq, const float* __restrict__ Wk,
    const float* __restrict__ Wv, const float* __restrict__ Wp,
    short* __restrict__ Wx, short* __restrict__ Wy)
{
    const int NW = 512 * C_DIM;  // 131072
    int fid = (blockIdx.x * 256 + threadIdx.x) * 8;
    const float* src; short* dst;
    if (fid < NW) { src = Wq + fid; dst = Wx + fid; }
    else {
        int g = fid - NW;
        dst = Wy + g;
        if (g < NW) src = Wk + g;
        else if (g < 2 * NW) src = Wv + (g - NW);
        else src = Wp + (g - 2 * NW);
    }
    bf16x8 o;
#pragma unroll
    for (int j = 0; j < 8; ++j) o[j] = f2bf(src[j]);
    *(bf16x8*)dst = o;
}

// ---------------------------------------------------------------------------
// MFMA projection: out[o, tok] = sum_c Wb[o,c] * Xt[tok,c] (+bias)
// kind 0: all o -> Q bf16 (h,b,n,d), bias0=bq
// kind 1: o<512 -> K (bias0=bk); o<1024 -> Vt bf16 (hb,d,n) (bias1=bv);
//         o>=1024 -> YP fp32 (b,n,d), no bias.
// Block: 64 o x 128 tokens; wave owns 16 o-rows. No LDS, no barriers.
// ---------------------------------------------------------------------------
__global__ __launch_bounds__(256) void proj_mfma(
    const short* __restrict__ Wb, const short* __restrict__ Xt,
    const float* __restrict__ bias0, const float* __restrict__ bias1,
    short* __restrict__ outA, short* __restrict__ outV, float* __restrict__ outY,
    int kind)
{
    const int o0 = blockIdx.y * 64;
    const int tok0 = blockIdx.x * 128;
    const int t = threadIdx.x, wave = t >> 6, lane = t & 63;
    const int lo = lane & 15, quad = lane >> 4;

    const short* wbase = Wb + (size_t)(o0 + wave * 16 + lo) * C_DIM + quad * 8;
    const short* xbase = Xt + (size_t)tok0 * C_DIM + quad * 8;

    f32x4 acc[8];
#pragma unroll
    for (int i = 0; i < 8; ++i) acc[i] = (f32x4){0.f, 0.f, 0.f, 0.f};

#pragma unroll 2
    for (int c0 = 0; c0 < C_DIM; c0 += 32) {
        bf16x8 a = *(const bf16x8*)(wbase + c0);
#pragma unroll
        for (int nt = 0; nt < 8; ++nt) {
            bf16x8 bx = *(const bf16x8*)(xbase + (size_t)(nt * 16 + lo) * C_DIM + c0);
            acc[nt] = MFMA16(a, bx, acc[nt]);
        }
    }

#pragma unroll
    for (int r = 0; r < 4; ++r) {
        const int o = o0 + wave * 16 + quad * 4 + r;
        float bval;
        if (kind == 0) bval = bias0[o];
        else if (o < 512) bval = bias0[o];
        else if (o < 1024) bval = bias1[o - 512];
        else bval = 0.f;
#pragma unroll
        for (int nt = 0; nt < 8; ++nt) {
            int tok = tok0 + nt * 16 + lo;
            int b = tok >> 11, n = tok & (N_DIM - 1);
            float v = acc[nt][r] + bval;
            if (kind == 0 || o < 512) {
                int h = o >> 6, d = o & 63;
                outA[(((size_t)h * B_DIM + b) * N_DIM + n) * HD + d] = f2bf(v);
            } else if (o < 1024) {
                int op = o - 512, h = op >> 6, d = op & 63;
                outV[(((size_t)h * B_DIM + b) * HD + d) * N_DIM + n] = f2bf(v);
            } else {
                outY[((size_t)b * N_DIM + n) * HD + (o - 1024)] = v;
            }
        }
    }
}

// ---------------------------------------------------------------------------
// rowsum: SC[hb][n] = 1 / sum_m exp(Q[n].K[m]). Block: 128 n-rows, full m.
// XCD swizzle: all 16 tiles of one hb share id%8. No LDS, no barriers.
// ---------------------------------------------------------------------------
__global__ __launch_bounds__(256) void rowsum_mfma(
    const short* __restrict__ Q, const short* __restrict__ K,
    float* __restrict__ SC)
{
    const int id = blockIdx.x;
    const int hb = ((id & 7) << 2) | ((id >> 3) & 3);
    const int n0 = (id >> 5) * 128;
    const int t = threadIdx.x, wave = t >> 6, lane = t & 63;
    const int lo = lane & 15, quad = lane >> 4;

    const short* qb = Q + ((size_t)hb * N_DIM + n0 + wave * 16 + lo) * HD + quad * 8;
    bf16x8 a0[2], a1[2];
#pragma unroll
    for (int s = 0; s < 2; ++s) {
        a0[s] = *(const bf16x8*)(qb + (size_t)s * 64 * HD);
        a1[s] = *(const bf16x8*)(qb + (size_t)s * 64 * HD + 32);
    }

    float sm[2][4];
#pragma unroll
    for (int s = 0; s < 2; ++s)
#pragma unroll
        for (int r = 0; r < 4; ++r) sm[s][r] = 0.f;

    const short* kb = K + (size_t)hb * N_DIM * HD + quad * 8;
    for (int m0 = 0; m0 < N_DIM; m0 += 64) {
#pragma unroll
        for (int mt = 0; mt < 4; ++mt) {
            const short* kp = kb + (size_t)(m0 + mt * 16 + lo) * HD;
            bf16x8 b0 = *(const bf16x8*)kp;
            bf16x8 b1 = *(const bf16x8*)(kp + 32);
#pragma unroll
            for (int s = 0; s < 2; ++s) {
                f32x4 c = {0.f, 0.f, 0.f, 0.f};
                c = MFMA16(a0[s], b0, c);
                c = MFMA16(a1[s], b1, c);
#pragma unroll
                for (int r = 0; r < 4; ++r) sm[s][r] += __expf(c[r]);
            }
        }
    }

#pragma unroll
    for (int sft = 1; sft < 16; sft <<= 1)
#pragma unroll
        for (int s = 0; s < 2; ++s)
#pragma unroll
            for (int r = 0; r < 4; ++r) sm[s][r] += __shfl_xor(sm[s][r], sft);

    if (lo == 0) {
#pragma unroll
        for (int s = 0; s < 2; ++s) {
            int row = n0 + s * 64 + wave * 16 + quad * 4;
#pragma unroll
            for (int r = 0; r < 4; ++r)
                SC[(size_t)hb * N_DIM + row + r] = 1.f / sm[s][r];
        }
    }
}

// ---------------------------------------------------------------------------
// V2[hb][d][n] = bf16( Vt[hb][d][n] * SC[hb][n] )
// ---------------------------------------------------------------------------
__global__ __launch_bounds__(256) void scale_v(
    const short* __restrict__ Vt, const float* __restrict__ SC,
    short* __restrict__ V2)
{
    int id = blockIdx.x * 256 + threadIdx.x;   // 0 .. 524287
    int ng = id & 255;
    int hd = id >> 8;                          // hb*64 + d, 0 .. 2047
    int hb = hd >> 6;
    size_t base = (size_t)hd * N_DIM + ng * 8;
    bf16x8 v = *(const bf16x8*)(Vt + base);
    const float* sp = SC + (size_t)hb * N_DIM + ng * 8;
    bf16x8 o;
#pragma unroll
    for (int i = 0; i < 8; ++i) o[i] = f2bf(bf2f(v[i]) * sp[i]);
    *(bf16x8*)(V2 + base) = o;
}

// ---------------------------------------------------------------------------
// attnout: out[m,d] = (g * sum_n exp(Q[n].K[m]) V2[n,d] + YP[m,d]) / (1+g)
// Block: 128-m tile x full n, XCD-swizzled by hb. Main loop barrier-free.
// ---------------------------------------------------------------------------
__global__ __launch_bounds__(256) void attnout_mfma(
    const short* __restrict__ Q, const short* __restrict__ K,
    const short* __restrict__ V2t, const float* __restrict__ YP,
    const float* __restrict__ gamma, float* __restrict__ out)
{
    const int id = blockIdx.x;
    const int hb = ((id & 7) << 2) | ((id >> 3) & 3);
    const int m0 = (id >> 5) * 128;
    const int h = hb >> 2, b = hb & 3;

    __shared__ short Pl[128][72];

    const int t = threadIdx.x, wave = t >> 6, lane = t & 63;
    const int lo = lane & 15, quad = lane >> 4;

    bf16x8 bk0[2], bk1[2];
#pragma unroll
    for (int s = 0; s < 2; ++s) {
        const short* kp = K + ((size_t)hb * N_DIM + m0 + s * 64 + wave * 16 + lo) * HD + quad * 8;
        bk0[s] = *(const bf16x8*)kp;
        bk1[s] = *(const bf16x8*)(kp + 32);
    }

    f32x4 oacc[2][4];
#pragma unroll
    for (int s = 0; s < 2; ++s)
#pragma unroll
        for (int dt = 0; dt < 4; ++dt) oacc[s][dt] = (f32x4){0.f, 0.f, 0.f, 0.f};

    const short* qb = Q + (size_t)hb * N_DIM * HD + quad * 8;
    const short* vb = V2t + (size_t)hb * HD * N_DIM + quad * 8;
    short* prow[2] = { &Pl[wave * 16 + lo][0], &Pl[64 + wave * 16 + lo][0] };

    for (int n0 = 0; n0 < N_DIM; n0 += 64) {
        // QK -> P (exp, unnormalized; 1/rowsum folded into V2t)
#pragma unroll
        for (int nt = 0; nt < 4; ++nt) {
            const short* qp = qb + (size_t)(n0 + nt * 16 + lo) * HD;
            bf16x8 a0 = *(const bf16x8*)qp;
            bf16x8 a1 = *(const bf16x8*)(qp + 32);
#pragma unroll
            for (int s = 0; s < 2; ++s) {
                f32x4 c = {0.f, 0.f, 0.f, 0.f};
                c = MFMA16(a0, bk0[s], c);
                c = MFMA16(a1, bk1[s], c);
                short4 pk;
                pk.x = f2bf(__expf(c[0]));
                pk.y = f2bf(__expf(c[1]));
                pk.z = f2bf(__expf(c[2]));
                pk.w = f2bf(__expf(c[3]));
                *(short4*)(prow[s] + nt * 16 + quad * 4) = pk;
            }
        }
        // PV
#pragma unroll
        for (int ks = 0; ks < 2; ++ks) {
            bf16x8 ap0 = *(const bf16x8*)(prow[0] + ks * 32 + quad * 8);
            bf16x8 ap1 = *(const bf16x8*)(prow[1] + ks * 32 + quad * 8);
#pragma unroll
            for (int dt = 0; dt < 4; ++dt) {
                bf16x8 bv = *(const bf16x8*)(vb + (size_t)(dt * 16 + lo) * N_DIM + n0 + ks * 32);
                oacc[0][dt] = MFMA16(ap0, bv, oacc[0][dt]);
                oacc[1][dt] = MFMA16(ap1, bv, oacc[1][dt]);
            }
        }
    }

    const float g = gamma[h];
    const float inv = 1.f / (1.f + g);
#pragma unroll
    for (int s = 0; s < 2; ++s)
#pragma unroll
        for (int dt = 0; dt < 4; ++dt) {
            int d = dt * 16 + lo;
#pragma unroll
            for (int r = 0; r < 4; ++r) {
                int m = m0 + s * 64 + wave * 16 + quad * 4 + r;
                out[((size_t)hb * N_DIM + m) * HD + d] =
                    (g * oacc[s][dt][r] + YP[((size_t)b * N_DIM + m) * HD + d]) * inv;
            }
        }
}

// ---------------------------------------------------------------------------
extern "C" void kernel_launch(void* const* d_in, const int* in_sizes, int n_in,
                              void* d_out, int out_size, void* d_ws, size_t ws_size,
                              hipStream_t stream) {
    const float* x     = (const float*)d_in[0];
    const float* y     = (const float*)d_in[1];
    const float* Wq    = (const float*)d_in[2];
    const float* bq    = (const float*)d_in[3];
    const float* Wk    = (const float*)d_in[4];
    const float* bk    = (const float*)d_in[5];
    const float* Wv    = (const float*)d_in[6];
    const float* bv    = (const float*)d_in[7];
    const float* Wp    = (const float*)d_in[8];
    const float* gamma = (const float*)d_in[9];
    float* out = (float*)d_out;

    const size_t XEL  = (size_t)B_DIM * C_DIM * N_DIM;  // 2,097,152
    const size_t QKV  = (size_t)HB * N_DIM * HD;        // 4,194,304

    short* Xt  = (short*)d_ws;
    short* Yt  = Xt + XEL;
    short* Wx  = Yt + XEL;            // 512*256
    short* Wy  = Wx + 512 * C_DIM;    // 1088*256
    short* Qb  = Wy + 1088 * C_DIM;
    short* Kb  = Qb + QKV;
    short* Vt  = Kb + QKV;
    short* V2  = Vt + QKV;
    float* YPb = (float*)(V2 + QKV);
    float* SC  = YPb + (size_t)B_DIM * N_DIM * HD;

    dim3 blk(256);
    cast_transpose<<<dim3(N_DIM / 64, C_DIM / 64, B_DIM), blk, 0, stream>>>(x, Xt);
    cast_transpose<<<dim3(N_DIM / 64, C_DIM / 64, B_DIM), blk, 0, stream>>>(y, Yt);
    cast_weights<<<dim3(200), blk, 0, stream>>>(Wq, Wk, Wv, Wp, Wx, Wy);

    proj_mfma<<<dim3(NTOK / 128, 8), blk, 0, stream>>>(
        Wx, Xt, bq, nullptr, Qb, nullptr, nullptr, 0);
    proj_mfma<<<dim3(NTOK / 128, 17), blk, 0, stream>>>(
        Wy, Yt, bk, bv, Kb, Vt, YPb, 1);

    rowsum_mfma<<<dim3(512), blk, 0, stream>>>(Qb, Kb, SC);
    scale_v<<<dim3(2048), blk, 0, stream>>>(Vt, SC, V2);   // FIX: was 1024 (half of V2 stayed poisoned)
    attnout_mfma<<<dim3(512), blk, 0, stream>>>(Qb, Kb, V2, YPb, gamma, out);
}

// Round 6
// 265.810 us; speedup vs baseline: 2.3533x; 1.3241x over previous
//
#include <hip/hip_runtime.h>
#include <math.h>

#define B_DIM 4
#define C_DIM 256
#define N_DIM 2048
#define H_DIM 8
#define HD    64
#define HB    32                 // H*B
#define NTOK  (B_DIM * N_DIM)    // 8192

typedef __attribute__((ext_vector_type(8))) short bf16x8;
typedef __attribute__((ext_vector_type(4))) float f32x4;

static __device__ __forceinline__ short f2bf(float f) {
    unsigned u = __builtin_bit_cast(unsigned, f);
    u += 0x7fffu + ((u >> 16) & 1u);
    return (short)(u >> 16);
}
static __device__ __forceinline__ float bf2f(short s) {
    unsigned u = ((unsigned)(unsigned short)s) << 16;
    return __builtin_bit_cast(float, u);
}

#define MFMA16(A, Bv, Cv) __builtin_amdgcn_mfma_f32_16x16x32_bf16(A, Bv, Cv, 0, 0, 0)

// Fragment-major layouts (each fragment = 64 lanes x 16 B, contiguous 1 KB):
//   QS/KS(hb, rt, ks, lane, j) = M[hb][n = rt*16 + (lane&15)][d = ks*32 + (lane>>4)*8 + j]
//   VS(hb, nb, ks, dt, lane, j) = Vsc[hb][d = dt*16+(lane&15)][n = nb*64+ks*32+(lane>>4)*8+j]

// ---------------------------------------------------------------------------
// cast+transpose: X (B,C,N) fp32 -> Xt (B,N,C) bf16
// ---------------------------------------------------------------------------
__global__ __launch_bounds__(256) void cast_transpose(
    const float* __restrict__ X, short* __restrict__ Xt)
{
    const int b = blockIdx.z, c0 = blockIdx.y * 64, n0 = blockIdx.x * 64;
    __shared__ float L[64][65];
    const int t = threadIdx.x;
    for (int i = t; i < 4096; i += 256) {
        int cc = i >> 6, nn = i & 63;
        L[cc][nn] = X[((size_t)b * C_DIM + c0 + cc) * N_DIM + n0 + nn];
    }
    __syncthreads();
#pragma unroll
    for (int half = 0; half < 2; ++half) {
        int row = half * 32 + (t >> 3);
        int c8 = (t & 7) * 8;
        bf16x8 o;
#pragma unroll
        for (int j = 0; j < 8; ++j) o[j] = f2bf(L[c8 + j][row]);
        *(bf16x8*)(Xt + ((size_t)b * N_DIM + n0 + row) * C_DIM + c0 + c8) = o;
    }
}

// ---------------------------------------------------------------------------
// weights fp32 -> bf16: Wx = Wq (512x256); Wy = [Wk; Wv; Wp] (1088x256)
// ---------------------------------------------------------------------------
__global__ __launch_bounds__(256) void cast_weights(
    const float* __restrict__ Wq, const float* __restrict__ Wk,
    const float* __restrict__ Wv, const float* __restrict__ Wp,
    short* __restrict__ Wx, short* __restrict__ Wy)
{
    const int NW = 512 * C_DIM;  // 131072
    int fid = (blockIdx.x * 256 + threadIdx.x) * 8;
    const float* src; short* dst;
    if (fid < NW) { src = Wq + fid; dst = Wx + fid; }
    else {
        int g = fid - NW;
        dst = Wy + g;
        if (g < NW) src = Wk + g;
        else if (g < 2 * NW) src = Wv + (g - NW);
        else src = Wp + (g - 2 * NW);
    }
    bf16x8 o;
#pragma unroll
    for (int j = 0; j < 8; ++j) o[j] = f2bf(src[j]);
    *(bf16x8*)dst = o;
}

// ---------------------------------------------------------------------------
// MFMA projection (unchanged from round 5, known-correct).
// ---------------------------------------------------------------------------
__global__ __launch_bounds__(256) void proj_mfma(
    const short* __restrict__ Wb, const short* __restrict__ Xt,
    const float* __restrict__ bias0, const float* __restrict__ bias1,
    short* __restrict__ outA, short* __restrict__ outV, float* __restrict__ outY,
    int kind)
{
    const int o0 = blockIdx.y * 64;
    const int tok0 = blockIdx.x * 128;
    const int t = threadIdx.x, wave = t >> 6, lane = t & 63;
    const int lo = lane & 15, quad = lane >> 4;

    const short* wbase = Wb + (size_t)(o0 + wave * 16 + lo) * C_DIM + quad * 8;
    const short* xbase = Xt + (size_t)tok0 * C_DIM + quad * 8;

    f32x4 acc[8];
#pragma unroll
    for (int i = 0; i < 8; ++i) acc[i] = (f32x4){0.f, 0.f, 0.f, 0.f};

#pragma unroll 2
    for (int c0 = 0; c0 < C_DIM; c0 += 32) {
        bf16x8 a = *(const bf16x8*)(wbase + c0);
#pragma unroll
        for (int nt = 0; nt < 8; ++nt) {
            bf16x8 bx = *(const bf16x8*)(xbase + (size_t)(nt * 16 + lo) * C_DIM + c0);
            acc[nt] = MFMA16(a, bx, acc[nt]);
        }
    }

#pragma unroll
    for (int r = 0; r < 4; ++r) {
        const int o = o0 + wave * 16 + quad * 4 + r;
        float bval;
        if (kind == 0) bval = bias0[o];
        else if (o < 512) bval = bias0[o];
        else if (o < 1024) bval = bias1[o - 512];
        else bval = 0.f;
#pragma unroll
        for (int nt = 0; nt < 8; ++nt) {
            int tok = tok0 + nt * 16 + lo;
            int b = tok >> 11, n = tok & (N_DIM - 1);
            float v = acc[nt][r] + bval;
            if (kind == 0 || o < 512) {
                int h = o >> 6, d = o & 63;
                outA[(((size_t)h * B_DIM + b) * N_DIM + n) * HD + d] = f2bf(v);
            } else if (o < 1024) {
                int op = o - 512, h = op >> 6, d = op & 63;
                outV[(((size_t)h * B_DIM + b) * HD + d) * N_DIM + n] = f2bf(v);
            } else {
                outY[((size_t)b * N_DIM + n) * HD + (o - 1024)] = v;
            }
        }
    }
}

// ---------------------------------------------------------------------------
// (hb,n,d) bf16 -> fragment-major QS/KS. Coalesced 16B writes.
// ---------------------------------------------------------------------------
__global__ __launch_bounds__(256) void qk_swizzle(
    const short* __restrict__ src, short* __restrict__ dst)
{
    int t = blockIdx.x * 256 + threadIdx.x;     // 0..524287
    int lane = t & 63, fidx = t >> 6;
    int ks = fidx & 1, rt = (fidx >> 1) & 127, hb = fidx >> 8;
    int lo = lane & 15, quad = lane >> 4;
    const short* sp = src + (size_t)(hb * N_DIM + rt * 16 + lo) * HD + ks * 32 + quad * 8;
    *(bf16x8*)(dst + (size_t)t * 8) = *(const bf16x8*)sp;
}

// ---------------------------------------------------------------------------
// Vt (hb,d,n) bf16 * SC -> fragment-major VS (PV B-operand fragments).
// ---------------------------------------------------------------------------
__global__ __launch_bounds__(256) void v_swizzle_scale(
    const short* __restrict__ Vt, const float* __restrict__ SC,
    short* __restrict__ VS)
{
    int t = blockIdx.x * 256 + threadIdx.x;     // 0..524287
    int lane = t & 63, fidx = t >> 6;
    int dt = fidx & 3, ks = (fidx >> 2) & 1, nb = (fidx >> 3) & 31, hb = fidx >> 8;
    int lo = lane & 15, quad = lane >> 4;
    int n = nb * 64 + ks * 32 + quad * 8;
    bf16x8 v = *(const bf16x8*)(Vt + (size_t)(hb * HD + dt * 16 + lo) * N_DIM + n);
    const float* sp = SC + (size_t)hb * N_DIM + n;
    bf16x8 o;
#pragma unroll
    for (int j = 0; j < 8; ++j) o[j] = f2bf(bf2f(v[j]) * sp[j]);
    *(bf16x8*)(VS + (size_t)t * 8) = o;
}

// ---------------------------------------------------------------------------
// rowsum: SC[hb][n] = 1 / sum_m exp(Q[n].K[m]). 128 n-rows/block, full m.
// All loads are coalesced fragment loads. No LDS, no barriers.
// ---------------------------------------------------------------------------
__global__ __launch_bounds__(256) void rowsum_mfma(
    const short* __restrict__ QS, const short* __restrict__ KS,
    float* __restrict__ SC)
{
    const int id = blockIdx.x;
    const int hb = ((id & 7) << 2) | ((id >> 3) & 3);
    const int n0 = (id >> 5) * 128;
    const int t = threadIdx.x, wave = t >> 6, lane = t & 63;
    const int lo = lane & 15, quad = lane >> 4;

    bf16x8 a0[2], a1[2];
#pragma unroll
    for (int s = 0; s < 2; ++s) {
        int rt = (n0 >> 4) + s * 4 + wave;
        a0[s] = *(const bf16x8*)(QS + ((size_t)(hb * 128 + rt) * 2 + 0) * 512 + lane * 8);
        a1[s] = *(const bf16x8*)(QS + ((size_t)(hb * 128 + rt) * 2 + 1) * 512 + lane * 8);
    }

    float sm[2][4];
#pragma unroll
    for (int s = 0; s < 2; ++s)
#pragma unroll
        for (int r = 0; r < 4; ++r) sm[s][r] = 0.f;

    for (int m0 = 0; m0 < N_DIM; m0 += 64) {
#pragma unroll
        for (int mt = 0; mt < 4; ++mt) {
            int rtk = (m0 >> 4) + mt;
            bf16x8 b0 = *(const bf16x8*)(KS + ((size_t)(hb * 128 + rtk) * 2 + 0) * 512 + lane * 8);
            bf16x8 b1 = *(const bf16x8*)(KS + ((size_t)(hb * 128 + rtk) * 2 + 1) * 512 + lane * 8);
#pragma unroll
            for (int s = 0; s < 2; ++s) {
                f32x4 c = {0.f, 0.f, 0.f, 0.f};
                c = MFMA16(a0[s], b0, c);
                c = MFMA16(a1[s], b1, c);
#pragma unroll
                for (int r = 0; r < 4; ++r) sm[s][r] += __expf(c[r]);
            }
        }
    }

#pragma unroll
    for (int sft = 1; sft < 16; sft <<= 1)
#pragma unroll
        for (int s = 0; s < 2; ++s)
#pragma unroll
            for (int r = 0; r < 4; ++r) sm[s][r] += __shfl_xor(sm[s][r], sft);

    if (lo == 0) {
#pragma unroll
        for (int s = 0; s < 2; ++s) {
            int row = n0 + s * 64 + wave * 16 + quad * 4;
#pragma unroll
            for (int r = 0; r < 4; ++r)
                SC[(size_t)hb * N_DIM + row + r] = 1.f / sm[s][r];
        }
    }
}

// ---------------------------------------------------------------------------
// attnout: out[m,d] = (g * sum_n exp(Q[n].K[m]) Vsc[n,d] + YP[m,d]) / (1+g)
// 128-m tile x full n. All global loads coalesced fragment loads; P goes
// through XOR-swizzled LDS (conflict-free); main loop barrier-free.
// ---------------------------------------------------------------------------
__global__ __launch_bounds__(256, 4) void attnout_mfma(
    const short* __restrict__ QS, const short* __restrict__ KS,
    const short* __restrict__ VS, const float* __restrict__ YP,
    const float* __restrict__ gamma, float* __restrict__ out)
{
    const int id = blockIdx.x;
    const int hb = ((id & 7) << 2) | ((id >> 3) & 3);
    const int m0 = (id >> 5) * 128;
    const int h = hb >> 2, b = hb & 3;

    __shared__ short Pl[128 * 64];   // [m_local][n_local], 8-short chunks XOR-swizzled by row&7

    const int t = threadIdx.x, wave = t >> 6, lane = t & 63;
    const int lo = lane & 15, quad = lane >> 4;

    bf16x8 bk0[2], bk1[2];
#pragma unroll
    for (int s = 0; s < 2; ++s) {
        int rt = (m0 >> 4) + s * 4 + wave;
        bk0[s] = *(const bf16x8*)(KS + ((size_t)(hb * 128 + rt) * 2 + 0) * 512 + lane * 8);
        bk1[s] = *(const bf16x8*)(KS + ((size_t)(hb * 128 + rt) * 2 + 1) * 512 + lane * 8);
    }

    f32x4 oacc[2][4];
#pragma unroll
    for (int s = 0; s < 2; ++s)
#pragma unroll
        for (int dt = 0; dt < 4; ++dt) oacc[s][dt] = (f32x4){0.f, 0.f, 0.f, 0.f};

    for (int n0 = 0; n0 < N_DIM; n0 += 64) {
        // ---- QK -> P (exp, unnormalized; 1/rowsum folded into VS) ----
#pragma unroll
        for (int nt = 0; nt < 4; ++nt) {
            int rt = (n0 >> 4) + nt;
            bf16x8 a0 = *(const bf16x8*)(QS + ((size_t)(hb * 128 + rt) * 2 + 0) * 512 + lane * 8);
            bf16x8 a1 = *(const bf16x8*)(QS + ((size_t)(hb * 128 + rt) * 2 + 1) * 512 + lane * 8);
#pragma unroll
            for (int s = 0; s < 2; ++s) {
                f32x4 c = {0.f, 0.f, 0.f, 0.f};
                c = MFMA16(a0, bk0[s], c);
                c = MFMA16(a1, bk1[s], c);
                short4 pk;
                pk.x = f2bf(__expf(c[0]));
                pk.y = f2bf(__expf(c[1]));
                pk.z = f2bf(__expf(c[2]));
                pk.w = f2bf(__expf(c[3]));
                int row = s * 64 + wave * 16 + lo;          // m_local (row&7 == lo&7)
                int chunk = nt * 2 + (quad >> 1);           // n_local/8
                *(short4*)(Pl + row * 64 + (((chunk ^ (lo & 7)) << 3) | ((quad & 1) << 2))) = pk;
            }
        }
        // ---- PV ----
        int nb = n0 >> 6;
#pragma unroll
        for (int ks = 0; ks < 2; ++ks) {
            bf16x8 ap[2];
#pragma unroll
            for (int s = 0; s < 2; ++s) {
                int row = s * 64 + wave * 16 + lo;
                ap[s] = *(const bf16x8*)(Pl + row * 64 + (((ks * 4 + quad) ^ (lo & 7)) << 3));
            }
#pragma unroll
            for (int dt = 0; dt < 4; ++dt) {
                bf16x8 bv = *(const bf16x8*)(
                    VS + ((size_t)(((hb * 32 + nb) * 2 + ks) * 4 + dt) * 64 + lane) * 8);
                oacc[0][dt] = MFMA16(ap[0], bv, oacc[0][dt]);
                oacc[1][dt] = MFMA16(ap[1], bv, oacc[1][dt]);
            }
        }
    }

    const float g = gamma[h];
    const float inv = 1.f / (1.f + g);
#pragma unroll
    for (int s = 0; s < 2; ++s)
#pragma unroll
        for (int dt = 0; dt < 4; ++dt) {
            int d = dt * 16 + lo;
#pragma unroll
            for (int r = 0; r < 4; ++r) {
                int m = m0 + s * 64 + wave * 16 + quad * 4 + r;
                out[((size_t)hb * N_DIM + m) * HD + d] =
                    (g * oacc[s][dt][r] + YP[((size_t)b * N_DIM + m) * HD + d]) * inv;
            }
        }
}

// ---------------------------------------------------------------------------
extern "C" void kernel_launch(void* const* d_in, const int* in_sizes, int n_in,
                              void* d_out, int out_size, void* d_ws, size_t ws_size,
                              hipStream_t stream) {
    const float* x     = (const float*)d_in[0];
    const float* y     = (const float*)d_in[1];
    const float* Wq    = (const float*)d_in[2];
    const float* bq    = (const float*)d_in[3];
    const float* Wk    = (const float*)d_in[4];
    const float* bk    = (const float*)d_in[5];
    const float* Wv    = (const float*)d_in[6];
    const float* bv    = (const float*)d_in[7];
    const float* Wp    = (const float*)d_in[8];
    const float* gamma = (const float*)d_in[9];
    float* out = (float*)d_out;

    const size_t XEL  = (size_t)B_DIM * C_DIM * N_DIM;  // 2,097,152
    const size_t QKV  = (size_t)HB * N_DIM * HD;        // 4,194,304

    short* Xt  = (short*)d_ws;        // [0, 2.1M)
    short* Yt  = Xt + XEL;            // [2.1M, 4.19M)
    short* Wx  = Yt + XEL;            // 512*256
    short* Wy  = Wx + 512 * C_DIM;    // 1088*256
    short* Qb  = Wy + 1088 * C_DIM;
    short* Kb  = Qb + QKV;
    short* Vt  = Kb + QKV;
    short* KS  = Vt + QKV;
    short* VS  = KS + QKV;
    float* YPb = (float*)(VS + QKV);
    float* SC  = YPb + (size_t)B_DIM * N_DIM * HD;
    short* QS  = (short*)d_ws;        // overlays Xt+Yt (dead after projections; sizes match)

    dim3 blk(256);
    cast_transpose<<<dim3(N_DIM / 64, C_DIM / 64, B_DIM), blk, 0, stream>>>(x, Xt);
    cast_transpose<<<dim3(N_DIM / 64, C_DIM / 64, B_DIM), blk, 0, stream>>>(y, Yt);
    cast_weights<<<dim3(200), blk, 0, stream>>>(Wq, Wk, Wv, Wp, Wx, Wy);

    proj_mfma<<<dim3(NTOK / 128, 8), blk, 0, stream>>>(
        Wx, Xt, bq, nullptr, Qb, nullptr, nullptr, 0);
    proj_mfma<<<dim3(NTOK / 128, 17), blk, 0, stream>>>(
        Wy, Yt, bk, bv, Kb, Vt, YPb, 1);

    qk_swizzle<<<dim3(2048), blk, 0, stream>>>(Qb, QS);
    qk_swizzle<<<dim3(2048), blk, 0, stream>>>(Kb, KS);

    rowsum_mfma<<<dim3(512), blk, 0, stream>>>(QS, KS, SC);
    v_swizzle_scale<<<dim3(2048), blk, 0, stream>>>(Vt, SC, VS);
    attnout_mfma<<<dim3(512), blk, 0, stream>>>(QS, KS, VS, YPb, gamma, out);
}